// Round 14
// baseline (400.809 us; speedup 1.0000x reference)
//
#include <hip/hip_runtime.h>
#include <math.h>

#define N_NODES 100000
#define N_EDGES 1600000
#define D 128
#define L_LAYERS 3
#define P_STATS 7
#define B_GRAPHS 64
#define BN_EPS 1e-5f
#define NEG_SLOPE 0.2f

#define NB 196        // buckets of 512 dst nodes
#define BCAP 10240
#define EPB 6400

#define NXCD 8
#define NBK 1568      // 64-node blocks, padded to multiple of 8 (1563 real)
#define NBK_PER_XCD (NBK / NXCD)  // 196

typedef __attribute__((ext_vector_type(8))) short bf16x8;
typedef __attribute__((ext_vector_type(4))) float f32x4;

static __device__ __forceinline__ short f2bf(float f) {
    union { float f; unsigned u; } v;
    v.f = f;
    unsigned r = v.u + 0x7fffu + ((v.u >> 16) & 1u);  // RNE
    return (short)(r >> 16);
}

static __device__ __forceinline__ float bf2f(short s) {
    union { unsigned u; float f; } v;
    v.u = ((unsigned)(unsigned short)s) << 16;
    return v.f;
}

// ---------------- setup: wconv + gproj + zero bucket_cnt ----------------
__global__ __launch_bounds__(256) void setup_kernel(const float* __restrict__ W1s,
                                                    const float* __restrict__ W2s,
                                                    const float* __restrict__ fcW,
                                                    short* __restrict__ wt,
                                                    const float* __restrict__ gs,
                                                    const float* __restrict__ statWs,
                                                    const float* __restrict__ statBs,
                                                    float* __restrict__ gproj,
                                                    int* __restrict__ bucket_cnt) {
    const int bid = blockIdx.x;
    const int tid = threadIdx.x;
    if (bid < 448) {
        int mid = bid >> 6;
        int chunk = bid & 63;
        const float* src = (mid < 3) ? (W1s + mid * D * D)
                                     : ((mid < 6) ? (W2s + (mid - 3) * D * D) : fcW);
        short* dstm = wt + mid * D * D;
        int i = chunk * 256 + tid;
        int k = i >> 7, n = i & 127;
        dstm[n * D + k] = f2bf(src[i]);
    } else if (bid < 448 + 96) {
        int p = (bid - 448) * 2 + (tid >> 7);
        int j = tid & 127;
        int b = p & 63;
        int l = p >> 6;
        float acc = statBs[l * D + j];
#pragma unroll
        for (int q = 0; q < P_STATS; ++q) {
            float g = gs[b * P_STATS + q];
            if (g != g) g = -100.0f;
            acc += g * statWs[(l * P_STATS + q) * D + j];
        }
        gproj[(l * B_GRAPHS + b) * D + j] = acc;
    } else {
        if (tid < NB) bucket_cnt[tid] = 0;
    }
}

// ---------------- CSR pass A ----------------
__global__ __launch_bounds__(256) void bucketA_kernel(const int* __restrict__ src,
                                                      const int* __restrict__ dst,
                                                      int* __restrict__ bucket_cnt,
                                                      int* __restrict__ bucketbuf) {
    __shared__ int hist[NB], base[NB], loc[NB];
    const int tid = threadIdx.x;
    const int e0 = blockIdx.x * EPB;
    for (int i = tid; i < NB; i += 256) { hist[i] = 0; loc[i] = 0; }
    __syncthreads();
    for (int i = tid; i < EPB; i += 256) {
        int d = dst[e0 + i];
        atomicAdd(&hist[d >> 9], 1);
    }
    __syncthreads();
    for (int i = tid; i < NB; i += 256)
        base[i] = hist[i] ? atomicAdd(&bucket_cnt[i], hist[i]) : 0;
    __syncthreads();
    for (int i = tid; i < EPB; i += 256) {
        int s = src[e0 + i];
        int d = dst[e0 + i];
        int b = d >> 9;
        int off = atomicAdd(&loc[b], 1);
        int idx = base[b] + off;
        if (idx < BCAP) bucketbuf[(size_t)b * BCAP + idx] = (s << 9) | (d & 511);
    }
}

// ---------------- CSR pass B ----------------
__global__ __launch_bounds__(256) void bucketB_kernel(const int* __restrict__ bucket_cnt,
                                                      const int* __restrict__ bucketbuf,
                                                      int* __restrict__ start,
                                                      int* __restrict__ csr_src) {
    __shared__ int hist[512];
    __shared__ int incl[512];
    __shared__ int cursor[512];
    __shared__ int red[256];
    __shared__ int sbase_sh;
    const int b = blockIdx.x;
    const int tid = threadIdx.x;
    const int cnt_b = min(bucket_cnt[b], BCAP);

    int partial = 0;
    for (int i = tid; i < b; i += 256) partial += min(bucket_cnt[i], BCAP);
    red[tid] = partial;
    __syncthreads();
    for (int off = 128; off > 0; off >>= 1) {
        if (tid < off) red[tid] += red[tid + off];
        __syncthreads();
    }
    if (tid == 0) sbase_sh = red[0];

    hist[tid] = 0;
    hist[tid + 256] = 0;
    __syncthreads();
    const int* bb = bucketbuf + (size_t)b * BCAP;
    for (int i = tid; i < cnt_b; i += 256) atomicAdd(&hist[bb[i] & 511], 1);
    __syncthreads();
    incl[tid] = hist[tid];
    incl[tid + 256] = hist[tid + 256];
    __syncthreads();
    for (int off = 1; off < 512; off <<= 1) {
        int i1 = tid + 256;
        int v0 = (tid >= off) ? incl[tid - off] : 0;
        int v1 = (i1 >= off) ? incl[i1 - off] : 0;
        __syncthreads();
        incl[tid] += v0;
        incl[i1] += v1;
        __syncthreads();
    }
    const int sbase = sbase_sh;
    int excl0 = incl[tid] - hist[tid];
    int excl1 = incl[tid + 256] - hist[tid + 256];
    cursor[tid] = excl0;
    cursor[tid + 256] = excl1;
    const int nbase = b << 9;
    if (nbase + tid < N_NODES) start[nbase + tid] = sbase + excl0;
    if (nbase + tid + 256 < N_NODES) start[nbase + tid + 256] = sbase + excl1;
    if (b == NB - 1 && tid == 0) start[N_NODES] = sbase + incl[511];
    __syncthreads();
    for (int i = tid; i < cnt_b; i += 256) {
        int e = bb[i];
        int pos = atomicAdd(&cursor[e & 511], 1);
        csr_src[sbase + pos] = e >> 9;
    }
}

// ---------------- aggregation over g + fused bias/LReLU/BN epilogue ----------------
// XCD-affine: grid = NBK*4; xcd = blockIdx%8; node-block nb = xcd*196 + t/4.
// Same nb->XCD map as initgemm/mlp2 so own-row reads and z writes stay XCD-local.
__global__ __launch_bounds__(256) void agg_ep_kernel(const short* __restrict__ g,
                                                     const int* __restrict__ start,
                                                     const int* __restrict__ csr_src,
                                                     const float* __restrict__ b1,
                                                     const float* __restrict__ gamma,
                                                     const float* __restrict__ beta,
                                                     const float* __restrict__ mean,
                                                     const float* __restrict__ var,
                                                     short* __restrict__ z) {
    const int xcd = blockIdx.x & 7;
    const int t = blockIdx.x >> 3;
    const int nb = xcd * NBK_PER_XCD + (t >> 2);
    int node = nb * 64 + (t & 3) * 16 + (threadIdx.x >> 4);
    if (node >= N_NODES) return;
    int c8 = threadIdx.x & 15;
    const bf16x8* g8 = (const bf16x8*)g;

    bf16x8 own = g8[node * 16 + c8];
    float acc[8];
#pragma unroll
    for (int i = 0; i < 8; ++i) acc[i] = bf2f(own[i]);

    int s = start[node];
    int e = start[node + 1];
    int k = s;
    for (; k + 8 <= e; k += 8) {
        int sn[8];
#pragma unroll
        for (int j = 0; j < 8; ++j) sn[j] = __builtin_nontemporal_load(&csr_src[k + j]);
        bf16x8 v[8];
#pragma unroll
        for (int j = 0; j < 8; ++j) v[j] = g8[sn[j] * 16 + c8];
#pragma unroll
        for (int j = 0; j < 8; ++j)
#pragma unroll
            for (int i = 0; i < 8; ++i) acc[i] += bf2f(v[j][i]);
    }
    for (; k + 4 <= e; k += 4) {
        int sn0 = __builtin_nontemporal_load(&csr_src[k]);
        int sn1 = __builtin_nontemporal_load(&csr_src[k + 1]);
        int sn2 = __builtin_nontemporal_load(&csr_src[k + 2]);
        int sn3 = __builtin_nontemporal_load(&csr_src[k + 3]);
        bf16x8 v0 = g8[sn0 * 16 + c8];
        bf16x8 v1 = g8[sn1 * 16 + c8];
        bf16x8 v2 = g8[sn2 * 16 + c8];
        bf16x8 v3 = g8[sn3 * 16 + c8];
#pragma unroll
        for (int i = 0; i < 8; ++i) acc[i] += bf2f(v0[i]);
#pragma unroll
        for (int i = 0; i < 8; ++i) acc[i] += bf2f(v1[i]);
#pragma unroll
        for (int i = 0; i < 8; ++i) acc[i] += bf2f(v2[i]);
#pragma unroll
        for (int i = 0; i < 8; ++i) acc[i] += bf2f(v3[i]);
    }
    for (; k < e; ++k) {
        int sn0 = __builtin_nontemporal_load(&csr_src[k]);
        bf16x8 v0 = g8[sn0 * 16 + c8];
#pragma unroll
        for (int i = 0; i < 8; ++i) acc[i] += bf2f(v0[i]);
    }

    const int f0 = c8 * 8;
    float4 bb0 = *(const float4*)&b1[f0];
    float4 bb1 = *(const float4*)&b1[f0 + 4];
    float4 gm0 = *(const float4*)&gamma[f0];
    float4 gm1 = *(const float4*)&gamma[f0 + 4];
    float4 bt0 = *(const float4*)&beta[f0];
    float4 bt1 = *(const float4*)&beta[f0 + 4];
    float4 mn0 = *(const float4*)&mean[f0];
    float4 mn1 = *(const float4*)&mean[f0 + 4];
    float4 vr0 = *(const float4*)&var[f0];
    float4 vr1 = *(const float4*)&var[f0 + 4];
    float bbv[8] = {bb0.x, bb0.y, bb0.z, bb0.w, bb1.x, bb1.y, bb1.z, bb1.w};
    float gmv[8] = {gm0.x, gm0.y, gm0.z, gm0.w, gm1.x, gm1.y, gm1.z, gm1.w};
    float btv[8] = {bt0.x, bt0.y, bt0.z, bt0.w, bt1.x, bt1.y, bt1.z, bt1.w};
    float mnv[8] = {mn0.x, mn0.y, mn0.z, mn0.w, mn1.x, mn1.y, mn1.z, mn1.w};
    float vrv[8] = {vr0.x, vr0.y, vr0.z, vr0.w, vr1.x, vr1.y, vr1.z, vr1.w};

    short pk[8];
#pragma unroll
    for (int i = 0; i < 8; ++i) {
        float t2 = acc[i] + bbv[i];
        t2 = (t2 > 0.f) ? t2 : NEG_SLOPE * t2;
        float sc = gmv[i] * rsqrtf(vrv[i] + BN_EPS);
        t2 = t2 * sc + (btv[i] - mnv[i] * sc);
        pk[i] = f2bf(t2);
    }
    *(bf16x8*)&z[node * D + f0] = *(bf16x8*)pk;
}

// ---------------- init GEMM: g0 = bf16(x) @ W1_0 (XCD-affine) ----------------
__global__ __launch_bounds__(256, 4) void initgemm_kernel(const float* __restrict__ x,
                                                          const short* __restrict__ Wt,
                                                          short* __restrict__ g_out) {
    __shared__ short sy[64 * 128];
    const int tid = threadIdx.x;
    const int wid = tid >> 6;
    const int lane = tid & 63;
    const int lr = lane & 15;
    const int lk = lane >> 4;

    const int xcd = blockIdx.x & 7;
    const int nb = xcd * NBK_PER_XCD + (blockIdx.x >> 3);
    const int blockNode = nb * 64;

    const int nlBase = (wid >> 1) * 32;
    const int nodeBase = blockNode + nlBase;
    const int featBase = (wid & 1) * 64;

    int nIdx[2];
#pragma unroll
    for (int mt = 0; mt < 2; ++mt) {
        int n = nodeBase + mt * 16 + lr;
        nIdx[mt] = (n < N_NODES) ? n : (N_NODES - 1);
    }

    f32x4 acc[4][2];
#pragma unroll
    for (int ft = 0; ft < 4; ++ft)
#pragma unroll
        for (int mt = 0; mt < 2; ++mt)
            acc[ft][mt] = (f32x4)(0.0f);

#pragma unroll
    for (int kt = 0; kt < 4; ++kt) {
        bf16x8 wfk[4];
#pragma unroll
        for (int ft = 0; ft < 4; ++ft)
            wfk[ft] = *(const bf16x8*)&Wt[(featBase + ft * 16 + lr) * D + kt * 32 + lk * 8];
        bf16x8 mf[2];
#pragma unroll
        for (int mt = 0; mt < 2; ++mt) {
            const float4* xp = (const float4*)&x[nIdx[mt] * D + kt * 32 + lk * 8];
            float4 a = xp[0], b = xp[1];
            short q[8];
            q[0] = f2bf(a.x); q[1] = f2bf(a.y); q[2] = f2bf(a.z); q[3] = f2bf(a.w);
            q[4] = f2bf(b.x); q[5] = f2bf(b.y); q[6] = f2bf(b.z); q[7] = f2bf(b.w);
            mf[mt] = *(bf16x8*)q;
        }
#pragma unroll
        for (int ft = 0; ft < 4; ++ft)
#pragma unroll
            for (int mt = 0; mt < 2; ++mt)
                acc[ft][mt] = __builtin_amdgcn_mfma_f32_16x16x32_bf16(wfk[ft], mf[mt],
                                                                      acc[ft][mt], 0, 0, 0);
    }

#pragma unroll
    for (int ft = 0; ft < 4; ++ft) {
        int f0 = featBase + ft * 16 + lk * 4;
#pragma unroll
        for (int mt = 0; mt < 2; ++mt) {
            int nl = nlBase + mt * 16 + lr;
            short4 pk;
#pragma unroll
            for (int r = 0; r < 4; ++r) ((short*)&pk)[r] = f2bf(acc[ft][mt][r]);
            int byteoff = nl * 256 + f0 * 2;
            byteoff ^= (nl & 7) << 4;
            *(short4*)((char*)sy + byteoff) = pk;
        }
    }
    __syncthreads();
#pragma unroll
    for (int it = 0; it < 4; ++it) {
        int c = tid + it * 256;
        int nl = c >> 4;
        int c8 = c & 15;
        int node = blockNode + nl;
        if (node < N_NODES) {
            int byteoff = nl * 256 + c8 * 16;
            byteoff ^= (nl & 7) << 4;
            bf16x8 v = *(const bf16x8*)((char*)sy + byteoff);
            *(bf16x8*)&g_out[node * D + c8 * 8] = v;
        }
    }
}

// ---------------- MLP: y=LReLU(z@W2+b2)+gproj -> h; g=h@Wn (or out=h@fcW+fcB) ----------------
template <bool FINAL>
__global__ __launch_bounds__(256, 4) void mlp2_kernel(
    const short* __restrict__ z,
    const short* __restrict__ W2t,
    const float* __restrict__ b2,
    const float* __restrict__ gproj, const int* __restrict__ batch,
    const short* __restrict__ Wnt,
    const float* __restrict__ fcb,
    float* __restrict__ outf, short* __restrict__ g_out) {
    __shared__ short sy[64 * 128];
    __shared__ float sB2[128], sFC[128];

    const int tid = threadIdx.x;
    const int wid = tid >> 6;
    const int lane = tid & 63;
    const int lr = lane & 15;
    const int lk = lane >> 4;

    if (tid < 128) {
        sB2[tid] = b2[tid];
        if (FINAL) sFC[tid] = fcb[tid];
    }
    __syncthreads();

    const int xcd = blockIdx.x & 7;
    const int nb = xcd * NBK_PER_XCD + (blockIdx.x >> 3);
    const int blockNode = nb * 64;

    const int nlBase = (wid >> 1) * 32;
    const int nodeBase = blockNode + nlBase;
    const int featBase = (wid & 1) * 64;

    int nIdx[2];
#pragma unroll
    for (int mt = 0; mt < 2; ++mt) {
        int n = nodeBase + mt * 16 + lr;
        nIdx[mt] = (n < N_NODES) ? n : (N_NODES - 1);
    }

    f32x4 acc[4][2];
#pragma unroll
    for (int ft = 0; ft < 4; ++ft)
#pragma unroll
        for (int mt = 0; mt < 2; ++mt)
            acc[ft][mt] = (f32x4)(0.0f);

    // GEMM A: z @ W2  (z is XCD-local L2 from agg)
#pragma unroll
    for (int kt = 0; kt < 4; ++kt) {
        bf16x8 wfk[4];
#pragma unroll
        for (int ft = 0; ft < 4; ++ft)
            wfk[ft] = *(const bf16x8*)&W2t[(featBase + ft * 16 + lr) * D + kt * 32 + lk * 8];
        bf16x8 zf[2];
#pragma unroll
        for (int mt = 0; mt < 2; ++mt)
            zf[mt] = *(const bf16x8*)&z[nIdx[mt] * D + kt * 32 + lk * 8];
#pragma unroll
        for (int ft = 0; ft < 4; ++ft)
#pragma unroll
            for (int mt = 0; mt < 2; ++mt)
                acc[ft][mt] = __builtin_amdgcn_mfma_f32_16x16x32_bf16(wfk[ft], zf[mt],
                                                                      acc[ft][mt], 0, 0, 0);
    }

    // epilogue: +b2, LReLU, +gproj -> h bf16 -> LDS (swizzled)
#pragma unroll
    for (int ft = 0; ft < 4; ++ft) {
        int f0 = featBase + ft * 16 + lk * 4;
#pragma unroll
        for (int mt = 0; mt < 2; ++mt) {
            int nl = nlBase + mt * 16 + lr;
            int bid = batch[nIdx[mt]];
            const float4 gp = *(const float4*)&gproj[bid * D + f0];
            short4 pk;
            float v0 = acc[ft][mt][0] + sB2[f0 + 0]; v0 = (v0 > 0.f) ? v0 : NEG_SLOPE * v0; v0 += gp.x;
            float v1 = acc[ft][mt][1] + sB2[f0 + 1]; v1 = (v1 > 0.f) ? v1 : NEG_SLOPE * v1; v1 += gp.y;
            float v2 = acc[ft][mt][2] + sB2[f0 + 2]; v2 = (v2 > 0.f) ? v2 : NEG_SLOPE * v2; v2 += gp.z;
            float v3 = acc[ft][mt][3] + sB2[f0 + 3]; v3 = (v3 > 0.f) ? v3 : NEG_SLOPE * v3; v3 += gp.w;
            pk.x = f2bf(v0); pk.y = f2bf(v1); pk.z = f2bf(v2); pk.w = f2bf(v3);
            int byteoff = nl * 256 + f0 * 2;
            byteoff ^= (nl & 7) << 4;
            *(short4*)((char*)sy + byteoff) = pk;
        }
    }
    __syncthreads();

    // GEMM B: h @ Wn (h from LDS)
#pragma unroll
    for (int ft = 0; ft < 4; ++ft)
#pragma unroll
        for (int mt = 0; mt < 2; ++mt)
            acc[ft][mt] = (f32x4)(0.0f);

#pragma unroll
    for (int kt = 0; kt < 4; ++kt) {
        bf16x8 wfk[4];
#pragma unroll
        for (int ft = 0; ft < 4; ++ft)
            wfk[ft] = *(const bf16x8*)&Wnt[(featBase + ft * 16 + lr) * D + kt * 32 + lk * 8];
        bf16x8 hf[2];
#pragma unroll
        for (int mt = 0; mt < 2; ++mt) {
            int nl = nlBase + mt * 16 + lr;
            int byteoff = nl * 256 + kt * 64 + lk * 16;
            byteoff ^= (nl & 7) << 4;
            hf[mt] = *(const bf16x8*)((char*)sy + byteoff);
        }
#pragma unroll
        for (int ft = 0; ft < 4; ++ft)
#pragma unroll
            for (int mt = 0; mt < 2; ++mt)
                acc[ft][mt] = __builtin_amdgcn_mfma_f32_16x16x32_bf16(wfk[ft], hf[mt],
                                                                      acc[ft][mt], 0, 0, 0);
    }

    if (FINAL) {
#pragma unroll
        for (int mt = 0; mt < 2; ++mt) {
            int node = nodeBase + mt * 16 + lr;
            if (node >= N_NODES) continue;
#pragma unroll
            for (int ft = 0; ft < 4; ++ft) {
                int f0 = featBase + ft * 16 + lk * 4;
                float4 o;
                o.x = acc[ft][mt][0] + sFC[f0 + 0];
                o.y = acc[ft][mt][1] + sFC[f0 + 1];
                o.z = acc[ft][mt][2] + sFC[f0 + 2];
                o.w = acc[ft][mt][3] + sFC[f0 + 3];
                *(float4*)&outf[node * D + f0] = o;
            }
        }
        return;
    }

    __syncthreads();
#pragma unroll
    for (int ft = 0; ft < 4; ++ft) {
        int f0 = featBase + ft * 16 + lk * 4;
#pragma unroll
        for (int mt = 0; mt < 2; ++mt) {
            int nl = nlBase + mt * 16 + lr;
            short4 pk;
#pragma unroll
            for (int r = 0; r < 4; ++r) ((short*)&pk)[r] = f2bf(acc[ft][mt][r]);
            int byteoff = nl * 256 + f0 * 2;
            byteoff ^= (nl & 7) << 4;
            *(short4*)((char*)sy + byteoff) = pk;
        }
    }
    __syncthreads();
#pragma unroll
    for (int it = 0; it < 4; ++it) {
        int c = tid + it * 256;
        int nl = c >> 4;
        int c8 = c & 15;
        int node = blockNode + nl;
        if (node < N_NODES) {
            int byteoff = nl * 256 + c8 * 16;
            byteoff ^= (nl & 7) << 4;
            bf16x8 v = *(const bf16x8*)((char*)sy + byteoff);
            *(bf16x8*)&g_out[node * D + c8 * 8] = v;
        }
    }
}

// ---------------- launch ----------------

extern "C" void kernel_launch(void* const* d_in, const int* in_sizes, int n_in,
                              void* d_out, int out_size, void* d_ws, size_t ws_size,
                              hipStream_t stream) {
    const float* x = (const float*)d_in[0];
    const int* ei = (const int*)d_in[1];
    const int* src = ei;
    const int* dst = ei + N_EDGES;
    const int* batch = (const int*)d_in[2];
    const float* gs = (const float*)d_in[3];
    const float* W1s = (const float*)d_in[4];
    const float* b1s = (const float*)d_in[5];
    const float* gammas = (const float*)d_in[6];
    const float* betas = (const float*)d_in[7];
    const float* means = (const float*)d_in[8];
    const float* vars = (const float*)d_in[9];
    const float* W2s = (const float*)d_in[10];
    const float* b2s = (const float*)d_in[11];
    const float* statWs = (const float*)d_in[12];
    const float* statBs = (const float*)d_in[13];
    const float* fcW = (const float*)d_in[14];
    const float* fcB = (const float*)d_in[15];
    float* out = (float*)d_out;

    char* ws = (char*)d_ws;
    auto alloc = [&](size_t bytes) {
        char* p = ws;
        ws += (bytes + 255) / 256 * 256;
        return p;
    };
    int* start = (int*)alloc((N_NODES + 1) * sizeof(int));
    int* csr_src = (int*)alloc(N_EDGES * sizeof(int));
    int* bucket_cnt = (int*)alloc(NB * sizeof(int));
    int* bucketbuf = (int*)alloc((size_t)NB * BCAP * sizeof(int));
    float* gproj = (float*)alloc((size_t)L_LAYERS * B_GRAPHS * D * sizeof(float));
    short* wt = (short*)alloc((size_t)7 * D * D * sizeof(short));
    short* g_buf = (short*)alloc((size_t)N_NODES * D * sizeof(short));
    short* z_buf = (short*)alloc((size_t)N_NODES * D * sizeof(short));

    setup_kernel<<<545, 256, 0, stream>>>(W1s, W2s, fcW, wt, gs, statWs, statBs, gproj,
                                          bucket_cnt);
    bucketA_kernel<<<N_EDGES / EPB, 256, 0, stream>>>(src, dst, bucket_cnt, bucketbuf);
    bucketB_kernel<<<NB, 256, 0, stream>>>(bucket_cnt, bucketbuf, start, csr_src);

    const int agg_blocks = NBK * 4;   // 6272 (XCD-affine, guarded)
    const int mlp_blocks = NBK;       // 1568 (XCD-affine, guarded)

    // g0 = bf16(x) @ W1_0
    initgemm_kernel<<<mlp_blocks, 256, 0, stream>>>(x, wt + 0 * D * D, g_buf);

    // layer 0
    agg_ep_kernel<<<agg_blocks, 256, 0, stream>>>(g_buf, start, csr_src, b1s + 0 * D,
                                                  gammas + 0 * D, betas + 0 * D, means + 0 * D,
                                                  vars + 0 * D, z_buf);
    mlp2_kernel<false><<<mlp_blocks, 256, 0, stream>>>(
        z_buf, wt + 3 * D * D, b2s + 0 * D, gproj + 0 * B_GRAPHS * D, batch,
        wt + 1 * D * D, nullptr, nullptr, g_buf);
    // layer 1
    agg_ep_kernel<<<agg_blocks, 256, 0, stream>>>(g_buf, start, csr_src, b1s + 1 * D,
                                                  gammas + 1 * D, betas + 1 * D, means + 1 * D,
                                                  vars + 1 * D, z_buf);
    mlp2_kernel<false><<<mlp_blocks, 256, 0, stream>>>(
        z_buf, wt + 4 * D * D, b2s + 1 * D, gproj + 1 * B_GRAPHS * D, batch,
        wt + 2 * D * D, nullptr, nullptr, g_buf);
    // layer 2 (+ fc_out)
    agg_ep_kernel<<<agg_blocks, 256, 0, stream>>>(g_buf, start, csr_src, b1s + 2 * D,
                                                  gammas + 2 * D, betas + 2 * D, means + 2 * D,
                                                  vars + 2 * D, z_buf);
    mlp2_kernel<true><<<mlp_blocks, 256, 0, stream>>>(
        z_buf, wt + 5 * D * D, b2s + 2 * D, gproj + 2 * B_GRAPHS * D, batch,
        wt + 6 * D * D, fcB, out, nullptr);
}